// Round 6
// baseline (290.543 us; speedup 1.0000x reference)
//
#include <hip/hip_runtime.h>
#include <hip/hip_bf16.h>

#define B_SZ 4
#define SEQ 8192
#define DIM 512
#define HEADS 8
#define DH 64
#define INNER 512
#define QKV_COLS 1536
#define M_TOT (B_SZ * SEQ)   // 32768
#define BHN (B_SZ * HEADS)   // 32

typedef __bf16 bf16x8 __attribute__((ext_vector_type(8)));
typedef __bf16 bf16x4 __attribute__((ext_vector_type(4)));
typedef float f32x4 __attribute__((ext_vector_type(4)));

__device__ __forceinline__ float elu1(float x) {
    return x > 0.f ? x + 1.f : __expf(x);   // elu(x)+1 = e^x for x<0
}

__device__ __forceinline__ void gl_lds16(const void* g, void* l) {
    __builtin_amdgcn_global_load_lds(
        (const __attribute__((address_space(1))) unsigned int*)g,
        (__attribute__((address_space(3))) unsigned int*)l, 16, 0, 0);
}

#define MFMA16(a, b, c) __builtin_amdgcn_mfma_f32_16x16x32_bf16(a, b, c, 0, 0, 0)

// ---------------- K0: all conversions in one launch ---------------------------
__global__ void convert_all(const float* __restrict__ x,
                            const float* __restrict__ w_qkv,
                            const float* __restrict__ w_out,
                            __bf16* __restrict__ xb,
                            __bf16* __restrict__ wqkv_t,   // [1536][512]
                            __bf16* __restrict__ wout_t) { // [512][512]
    const int NX = M_TOT * DIM / 4;          // float4 chunks of x
    int id = blockIdx.x * 256 + threadIdx.x;
    if (id < NX) {
        float4 f = reinterpret_cast<const float4*>(x)[id];
        bf16x4 h = {(__bf16)f.x, (__bf16)f.y, (__bf16)f.z, (__bf16)f.w};
        reinterpret_cast<bf16x4*>(xb)[id] = h;
        return;
    }
    int id2 = id - NX;
    if (id2 < QKV_COLS * DIM) {
        int n = id2 / DIM, k = id2 % DIM;
        wqkv_t[id2] = (__bf16)w_qkv[k * QKV_COLS + n];
    } else {
        int id3 = id2 - QKV_COLS * DIM;
        if (id3 < INNER * DIM) {
            int n = id3 / DIM, k = id3 % DIM;
            wout_t[id3] = (__bf16)w_out[k * DIM + n];
        }
    }
}

// ---------------- K1: qkv GEMM (128^2 tile + XCD slab swizzle, ~68.7us) -------
// Slab swizzle verified R5: FETCH 73->32 MB (A fetched once). Kernel is
// internally schedule-bound (MfmaUtil ~32%) -- structure frozen.
#define TSTR 136   // epilogue transpose stride (272 B) -> 16B-aligned rows
__launch_bounds__(256, 2)
__global__ void gemm_qkv(const __bf16* __restrict__ xb,
                         const __bf16* __restrict__ wqkv_t,
                         __bf16* __restrict__ q_ws,    // [b,h,n,dh]
                         __bf16* __restrict__ kT_ws,   // [b,h,dh,n]
                         __bf16* __restrict__ vT_ws) { // [b,h,dh,n]
    __shared__ __attribute__((aligned(16))) char smem[128 * TSTR * 2]; // 34816 B
    __bf16* As = (__bf16*)smem;              // [128][64] packed, 16 KB
    __bf16* Bs = (__bf16*)(smem + 16384);    // [128][64] packed, 16 KB
    __bf16* T  = (__bf16*)smem;              // [128][TSTR] epilogue transpose

    const int tid = threadIdx.x;
    const int wid = tid >> 6;
    const int lane = tid & 63;
    const int wm = wid >> 1, wn = wid & 1;
    const int lq = lane >> 4, lr = lane & 15;
    // bijective XCD slab swizzle (dispatch order is x-fastest: f = x + y*256)
    const int f  = blockIdx.y * gridDim.x + blockIdx.x;
    const int xc = f & 7, sl = f >> 3;       // sl in [0,384)
    const int ml = sl / 12, nn = sl % 12;    // 32 m-panels per XCD, n fastest
    const int m0 = (xc * 32 + ml) * 128;
    const int n0 = nn * 128;
    const int lrow = lane >> 3;              // staging: row within 8-row group
    const int lsw  = ((lane & 7) ^ lrow) * 8; // swizzled source chunk (elems)

    f32x4 acc[4][4] = {};

    for (int kb = 0; kb < DIM; kb += 64) {
#pragma unroll
        for (int t = 0; t < 4; ++t) {
            int qi = wid * 4 + t;            // instruction index 0..15
            int row = qi * 8 + lrow;
            gl_lds16(&xb[(size_t)(m0 + row) * DIM + kb + lsw], &As[qi * 512]);
            gl_lds16(&wqkv_t[(size_t)(n0 + row) * DIM + kb + lsw], &Bs[qi * 512]);
        }
        __syncthreads();
#pragma unroll
        for (int ks = 0; ks < 2; ++ks) {
            const int csw = ((ks * 4 + lq) ^ (lr & 7)) * 8;  // swizzled read slot
            bf16x8 af[4], bfv[4];
#pragma unroll
            for (int i = 0; i < 4; ++i)
                af[i] = *reinterpret_cast<const bf16x8*>(
                    &As[(wm * 64 + i * 16 + lr) * 64 + csw]);
#pragma unroll
            for (int j = 0; j < 4; ++j)
                bfv[j] = *reinterpret_cast<const bf16x8*>(
                    &Bs[(wn * 64 + j * 16 + lr) * 64 + csw]);
#pragma unroll
            for (int i = 0; i < 4; ++i)
#pragma unroll
                for (int j = 0; j < 4; ++j)
                    acc[i][j] = MFMA16(af[i], bfv[j], acc[i][j]);
        }
        __syncthreads();
    }

    const int which = n0 / INNER;            // 0=q 1=k 2=v (block-uniform)
    const int n0w = n0 % INNER;
    const int b = m0 / SEQ;
    const int nbase = m0 % SEQ;

    if (which == 0) {
        // T[row][col]: scalar writes with elu, then coalesced [n][dh] stores
#pragma unroll
        for (int i = 0; i < 4; ++i)
#pragma unroll
            for (int j = 0; j < 4; ++j) {
                int col = wn * 64 + j * 16 + lr;
#pragma unroll
                for (int r = 0; r < 4; ++r)
                    T[(wm * 64 + i * 16 + lq * 4 + r) * TSTR + col] =
                        (__bf16)elu1(acc[i][j][r]);
            }
        __syncthreads();
#pragma unroll
        for (int it = 0; it < 8; ++it) {
            int c = tid + it * 256;          // 2048 chunks of 8
            int row = c >> 4, dc = (c & 15) * 8;
            bf16x8 v = *reinterpret_cast<const bf16x8*>(&T[row * TSTR + dc]);
            int col = n0w + dc;
            int h = col >> 6, d = col & 63;
            *reinterpret_cast<bf16x8*>(
                &q_ws[(((size_t)(b * HEADS + h)) * SEQ + nbase + row) * DH + d]) = v;
        }
    } else {
        __bf16* dst = (which == 1) ? kT_ws : vT_ws;
        // T[col][row]: vector 8B writes, then coalesced [dh][n] stores
#pragma unroll
        for (int i = 0; i < 4; ++i)
#pragma unroll
            for (int j = 0; j < 4; ++j) {
                int col = wn * 64 + j * 16 + lr;
                int rowb = wm * 64 + i * 16 + lq * 4;
                bf16x4 h4;
#pragma unroll
                for (int r = 0; r < 4; ++r) {
                    float v = acc[i][j][r];
                    h4[r] = (__bf16)((which == 1) ? elu1(v) : v);
                }
                *reinterpret_cast<bf16x4*>(&T[col * TSTR + rowb]) = h4;
            }
        __syncthreads();
#pragma unroll
        for (int it = 0; it < 8; ++it) {
            int c = tid + it * 256;
            int colIdx = c >> 4, rc = (c & 15) * 8;
            bf16x8 v = *reinterpret_cast<const bf16x8*>(&T[colIdx * TSTR + rc]);
            int gcol = n0w + colIdx;
            int h = gcol >> 6, d = gcol & 63;
            *reinterpret_cast<bf16x8*>(
                &dst[(((size_t)(b * HEADS + h)) * DH + d) * SEQ + nbase + rc]) = v;
        }
    }
}

// ---------------- K2: kv^T[bh][m][d] = sum_n K^T[d][n]*V[n][m]; + ksum fused --
__launch_bounds__(256, 2)
__global__ void kv_reduce(const __bf16* __restrict__ kT,
                          const __bf16* __restrict__ vT,
                          float* __restrict__ kv_t,     // [bh][m][d] fp32
                          float* __restrict__ ksum) {   // [bh][d]
    __shared__ __attribute__((aligned(16))) __bf16 Ks[64][136];
    __shared__ __attribute__((aligned(16))) __bf16 Vs[64][136];
    const int tid = threadIdx.x;
    const int wid = tid >> 6;
    const int lane = tid & 63;
    const int lq = lane >> 4, lr = lane & 15;
    const int bh = blockIdx.y;
    const int n0 = blockIdx.x * 512;
    const size_t base = (size_t)bh * DH * SEQ;
    f32x4 acc[4] = {};
    f32x4 acc1 = {};
    bf16x8 ones8;
#pragma unroll
    for (int e = 0; e < 8; ++e) ones8[e] = (__bf16)1.f;

    for (int ch = 0; ch < 4; ++ch) {
        int nc = n0 + ch * 128;
#pragma unroll
        for (int t = 0; t < 4; ++t) {
            int c = tid + t * 256;              // 1024 chunks: 64 rows x 16
            int row = c >> 4, kc = (c & 15) * 8;
            *reinterpret_cast<bf16x8*>(&Ks[row][kc]) =
                *reinterpret_cast<const bf16x8*>(&kT[base + (size_t)row * SEQ + nc + kc]);
            *reinterpret_cast<bf16x8*>(&Vs[row][kc]) =
                *reinterpret_cast<const bf16x8*>(&vT[base + (size_t)row * SEQ + nc + kc]);
        }
        __syncthreads();
#pragma unroll
        for (int ks = 0; ks < 4; ++ks) {
            bf16x8 a = *reinterpret_cast<const bf16x8*>(&Ks[wid * 16 + lr][ks * 32 + lq * 8]);
            acc1 = MFMA16(a, ones8, acc1);
#pragma unroll
            for (int j = 0; j < 4; ++j) {
                bf16x8 b = *reinterpret_cast<const bf16x8*>(&Vs[j * 16 + lr][ks * 32 + lq * 8]);
                acc[j] = MFMA16(a, b, acc[j]);
            }
        }
        __syncthreads();
    }
    float* dst = kv_t + (size_t)bh * DH * DH;
#pragma unroll
    for (int j = 0; j < 4; ++j) {
        int m = j * 16 + lr;
#pragma unroll
        for (int r = 0; r < 4; ++r) {
            int d = wid * 16 + lq * 4 + r;
            atomicAdd(&dst[m * DH + d], acc[j][r]);
        }
    }
    if (lr == 0) {
#pragma unroll
        for (int r = 0; r < 4; ++r)
            atomicAdd(&ksum[bh * DH + wid * 16 + lq * 4 + r], acc1[r]);
    }
}

// ---------------- K3: fused attn + output GEMM (register-budgeted v2) ---------
// R4 failed on VGPR: acc[4][8]=128 VGPR under bounds(512,2)=128-cap -> spills.
// v2: 64-row tile, 256 threads, bounds(256,2) -> 256-VGPR cap, need ~230.
// LDS 24.8 KB -> 2 blocks/CU (512 blocks) for inter-block barrier overlap.
// Math path identical to R2 split (fp32 z-dot, bf16 attn rounding point).
__launch_bounds__(256, 2)
__global__ void attn_out(const __bf16* __restrict__ q_ws,   // [b,h,n,dh]
                         const float* __restrict__ kv_t,    // [bh][m][d]
                         const float* __restrict__ ksum,    // [bh][d]
                         const __bf16* __restrict__ wout_t, // [c][k]
                         const float* __restrict__ b_out,
                         float* __restrict__ out) {
    __shared__ __attribute__((aligned(16))) __bf16 kvs[2][64 * 64];   // swizzled
    __shared__ __attribute__((aligned(16))) __bf16 attn_lds[64 * 64]; // swizzled
    __shared__ float zs[64];

    const int tid = threadIdx.x;
    const int wid = tid >> 6, lane = tid & 63;       // 4 waves
    const int lq = lane >> 4, lr = lane & 15;
    const int wn = wid;                              // wave = 64 rows x 128 cols
    const int m0 = blockIdx.x * 64;
    const int b = m0 / SEQ;
    const int nseq = m0 % SEQ;

    f32x4 acc[4][8] = {};   // out tile: rows i*16+lq*4+r, cols wn*128+n*16+lr

    // kv staging: thread -> (m = tid>>2, chunks c0,c0+1), swizzle chunk c^(m&7)
    auto stage_kv = [&](int buf, int h) {
        int m = tid >> 2, c0 = (tid & 3) * 2;
        const float* src = &kv_t[(((size_t)(b * 8 + h)) * 64 + m) * 64 + c0 * 8];
#pragma unroll
        for (int u = 0; u < 2; ++u) {
            float4 f0 = *reinterpret_cast<const float4*>(src + u * 8);
            float4 f1 = *reinterpret_cast<const float4*>(src + u * 8 + 4);
            bf16x8 v = {(__bf16)f0.x, (__bf16)f0.y, (__bf16)f0.z, (__bf16)f0.w,
                        (__bf16)f1.x, (__bf16)f1.y, (__bf16)f1.z, (__bf16)f1.w};
            *reinterpret_cast<bf16x8*>(
                &kvs[buf][m * 64 + (((c0 + u) ^ (m & 7)) * 8)]) = v;
        }
    };

    stage_kv(0, 0);
    __syncthreads();

    for (int h = 0; h < 8; ++h) {
        const int buf = h & 1;
        const size_t qb = (((size_t)(b * 8 + h)) * SEQ + nseq) * DH;

        // ---- z: 4 threads per row (64 rows), fp32 ksum dot ----
        {
            int row = tid >> 2, part = tid & 3;
            const __bf16* qp = &q_ws[qb + (size_t)row * DH + part * 16];
            bf16x8 v0 = *reinterpret_cast<const bf16x8*>(qp);
            bf16x8 v1 = *reinterpret_cast<const bf16x8*>(qp + 8);
            const float* kp = &ksum[(b * 8 + h) * 64 + part * 16];
            float s = 0.f;
#pragma unroll
            for (int j = 0; j < 8; ++j) s += (float)v0[j] * kp[j];
#pragma unroll
            for (int j = 0; j < 8; ++j) s += (float)v1[j] * kp[8 + j];
            s += __shfl_xor(s, 1, 64);
            s += __shfl_xor(s, 2, 64);
            if (part == 0) zs[row] = 1.f / (s + 1e-6f);
        }

        // ---- GEMM1: wave wid owns rows r0..r0+16; attn_h -> swizzled LDS ----
        {
            const int r0 = wid * 16;
            bf16x8 qa[2];
#pragma unroll
            for (int ks = 0; ks < 2; ++ks)
                qa[ks] = *reinterpret_cast<const bf16x8*>(
                    &q_ws[qb + (size_t)(r0 + lr) * DH + ks * 32 + lq * 8]);
            f32x4 acc1[4] = {};
#pragma unroll
            for (int ks = 0; ks < 2; ++ks)
#pragma unroll
                for (int j = 0; j < 4; ++j) {
                    int mr = j * 16 + lr;
                    bf16x8 bk = *reinterpret_cast<const bf16x8*>(
                        &kvs[buf][mr * 64 + (((ks * 4 + lq) ^ (mr & 7)) * 8)]);
                    acc1[j] = MFMA16(qa[ks], bk, acc1[j]);
                }
            asm volatile("s_waitcnt lgkmcnt(0)" ::: "memory"); // own-wave zs rows
            float zr[4];
#pragma unroll
            for (int r = 0; r < 4; ++r) zr[r] = zs[r0 + lq * 4 + r];
#pragma unroll
            for (int j = 0; j < 4; ++j)
#pragma unroll
                for (int r = 0; r < 4; ++r) {
                    int row = r0 + lq * 4 + r;
                    int chk = j * 2 + (lr >> 3);
                    attn_lds[row * 64 + ((chk ^ (row & 7)) * 8) + (lr & 7)] =
                        (__bf16)(acc1[j][r] * zr[r]);
                }
        }
        if (h < 7) stage_kv(buf ^ 1, h + 1);
        __syncthreads();

        // ---- GEMM2: out += attn_h @ wout_h (B preloaded in 4-n half-clusters)
        {
            bf16x8 af[4][2];
#pragma unroll
            for (int i = 0; i < 4; ++i)
#pragma unroll
                for (int ks = 0; ks < 2; ++ks) {
                    int arow = i * 16 + lr;
                    af[i][ks] = *reinterpret_cast<const bf16x8*>(
                        &attn_lds[arow * 64 + (((ks * 4 + lq) ^ (arow & 7)) * 8)]);
                }
#pragma unroll
            for (int half = 0; half < 2; ++half) {
                bf16x8 bw[4][2];
#pragma unroll
                for (int nn = 0; nn < 4; ++nn) {
                    int c = wn * 128 + (half * 4 + nn) * 16 + lr;
                    const __bf16* wp = &wout_t[(size_t)c * 512 + h * 64 + lq * 8];
                    bw[nn][0] = *reinterpret_cast<const bf16x8*>(wp);
                    bw[nn][1] = *reinterpret_cast<const bf16x8*>(wp + 32);
                }
                __builtin_amdgcn_s_setprio(1);
#pragma unroll
                for (int nn = 0; nn < 4; ++nn)
#pragma unroll
                    for (int i = 0; i < 4; ++i) {
                        acc[i][half * 4 + nn] = MFMA16(af[i][0], bw[nn][0], acc[i][half * 4 + nn]);
                        acc[i][half * 4 + nn] = MFMA16(af[i][1], bw[nn][1], acc[i][half * 4 + nn]);
                    }
                __builtin_amdgcn_s_setprio(0);
            }
        }
        __syncthreads();
    }

    // ---- epilogue: out = acc + bias (fp32) ----
#pragma unroll
    for (int n = 0; n < 8; ++n) {
        int col = wn * 128 + n * 16 + lr;
        float bias = b_out[col];
#pragma unroll
        for (int i = 0; i < 4; ++i) {
            int row = m0 + i * 16 + lq * 4;
#pragma unroll
            for (int r = 0; r < 4; ++r)
                out[(size_t)(row + r) * DIM + col] = acc[i][n][r] + bias;
        }
    }
}

// ------------------------------------------------------------------------------
extern "C" void kernel_launch(void* const* d_in, const int* in_sizes, int n_in,
                              void* d_out, int out_size, void* d_ws, size_t ws_size,
                              hipStream_t stream) {
    (void)in_sizes; (void)n_in; (void)out_size; (void)ws_size;
    const float* x     = (const float*)d_in[0];
    const float* w_qkv = (const float*)d_in[1];
    const float* w_out = (const float*)d_in[2];
    const float* b_out = (const float*)d_in[3];
    float* out = (float*)d_out;

    char* ws = (char*)d_ws;
    size_t off = 0;
    auto alloc = [&](size_t bytes) {
        char* p = ws + off;
        off += (bytes + 255) & ~(size_t)255;
        return p;
    };
    __bf16* xb     = (__bf16*)alloc((size_t)M_TOT * DIM * 2);    // 33.5 MB
    __bf16* q_ws   = (__bf16*)alloc((size_t)BHN * SEQ * DH * 2);
    __bf16* kT_ws  = (__bf16*)alloc((size_t)BHN * SEQ * DH * 2);
    __bf16* vT_ws  = (__bf16*)alloc((size_t)BHN * SEQ * DH * 2);
    float*  kv_t   = (float*)alloc((size_t)BHN * DH * DH * 4 + (size_t)BHN * DH * 4);
    float*  ksum   = kv_t + (size_t)BHN * DH * DH;
    __bf16* wqkv_t = (__bf16*)alloc((size_t)QKV_COLS * DIM * 2);
    __bf16* wout_t = (__bf16*)alloc((size_t)INNER * DIM * 2);

    hipMemsetAsync(kv_t, 0, (size_t)BHN * DH * DH * 4 + (size_t)BHN * DH * 4, stream);
    convert_all<<<dim3(M_TOT * DIM / 4 / 256 + (QKV_COLS * DIM + INNER * DIM) / 256),
                  256, 0, stream>>>(x, w_qkv, w_out, xb, wqkv_t, wout_t);
    gemm_qkv<<<dim3(M_TOT / 128, QKV_COLS / 128), 256, 0, stream>>>(
        xb, wqkv_t, q_ws, kT_ws, vT_ws);
    kv_reduce<<<dim3(16, BHN), 256, 0, stream>>>(kT_ws, vT_ws, kv_t, ksum);
    attn_out<<<dim3(M_TOT / 64), 256, 0, stream>>>(
        q_ws, kv_t, ksum, wout_t, b_out, out);
}

// Round 7
// 264.348 us; speedup vs baseline: 1.0991x; 1.0991x over previous
//
#include <hip/hip_runtime.h>
#include <hip/hip_bf16.h>

#define B_SZ 4
#define SEQ 8192
#define DIM 512
#define HEADS 8
#define DH 64
#define INNER 512
#define QKV_COLS 1536
#define M_TOT (B_SZ * SEQ)   // 32768
#define BHN (B_SZ * HEADS)   // 32

typedef __bf16 bf16x8 __attribute__((ext_vector_type(8)));
typedef __bf16 bf16x4 __attribute__((ext_vector_type(4)));
typedef float f32x4 __attribute__((ext_vector_type(4)));

__device__ __forceinline__ float elu1(float x) {
    return x > 0.f ? x + 1.f : __expf(x);   // elu(x)+1 = e^x for x<0
}

__device__ __forceinline__ void gl_lds16(const void* g, void* l) {
    __builtin_amdgcn_global_load_lds(
        (const __attribute__((address_space(1))) unsigned int*)g,
        (__attribute__((address_space(3))) unsigned int*)l, 16, 0, 0);
}

#define MFMA16(a, b, c) __builtin_amdgcn_mfma_f32_16x16x32_bf16(a, b, c, 0, 0, 0)
#define BARRIER() asm volatile("s_barrier" ::: "memory")

// ---------------- K0: conversions; weights via LDS tile transpose -------------
// Old version read w_qkv columns at stride 6 KB (uncoalesced scalar fp32).
// New: 32x32 fp32 tile, coalesced reads, padded LDS, coalesced bf16 writes.
#define XBLKS 16384                      // M_TOT*DIM/4/256
__global__ void convert_all(const float* __restrict__ x,
                            const float* __restrict__ w_qkv,
                            const float* __restrict__ w_out,
                            __bf16* __restrict__ xb,
                            __bf16* __restrict__ wqkv_t,   // [1536][512]
                            __bf16* __restrict__ wout_t) { // [512][512]
    const int tid = threadIdx.x;
    const int bid = blockIdx.x;
    if (bid < XBLKS) {
        int id = bid * 256 + tid;
        float4 f = reinterpret_cast<const float4*>(x)[id];
        bf16x4 h = {(__bf16)f.x, (__bf16)f.y, (__bf16)f.z, (__bf16)f.w};
        reinterpret_cast<bf16x4*>(xb)[id] = h;
        return;
    }
    __shared__ float tile[32][33];
    int tb = bid - XBLKS;
    const float* src; __bf16* dst; int k0, n0, scols;
    if (tb < 768) {                       // w_qkv: 16 k-tiles x 48 n-tiles
        int kt = tb & 15, nt = tb >> 4;
        k0 = kt * 32; n0 = nt * 32; src = w_qkv; dst = wqkv_t; scols = QKV_COLS;
    } else {                              // w_out: 16 x 16 tiles
        tb -= 768;
        int kt = tb & 15, nt = tb >> 4;
        k0 = kt * 32; n0 = nt * 32; src = w_out; dst = wout_t; scols = DIM;
    }
    {
        int c = tid & 31, r = tid >> 5;   // coalesced fp32 reads (n contiguous)
#pragma unroll
        for (int p = 0; p < 4; ++p)
            tile[r + p * 8][c] = src[(size_t)(k0 + r + p * 8) * scols + n0 + c];
    }
    __syncthreads();
    {
        int k = tid & 31, n = tid >> 5;   // coalesced bf16 writes (k contiguous)
#pragma unroll
        for (int p = 0; p < 4; ++p)
            dst[(size_t)(n0 + n + p * 8) * DIM + k0 + k] =
                (__bf16)tile[k][n + p * 8];
    }
}

// ---------------- K1: qkv GEMM (128^2 tile + XCD slab swizzle, ~67us) ---------
// Slab swizzle verified R5: FETCH 73->32 MB (A fetched once). Structure frozen.
#define TSTR 136   // epilogue transpose stride (272 B) -> 16B-aligned rows
__launch_bounds__(256, 2)
__global__ void gemm_qkv(const __bf16* __restrict__ xb,
                         const __bf16* __restrict__ wqkv_t,
                         __bf16* __restrict__ q_ws,    // [b,h,n,dh]
                         __bf16* __restrict__ kT_ws,   // [b,h,dh,n]
                         __bf16* __restrict__ vT_ws) { // [b,h,dh,n]
    __shared__ __attribute__((aligned(16))) char smem[128 * TSTR * 2]; // 34816 B
    __bf16* As = (__bf16*)smem;              // [128][64] packed, 16 KB
    __bf16* Bs = (__bf16*)(smem + 16384);    // [128][64] packed, 16 KB
    __bf16* T  = (__bf16*)smem;              // [128][TSTR] epilogue transpose

    const int tid = threadIdx.x;
    const int wid = tid >> 6;
    const int lane = tid & 63;
    const int wm = wid >> 1, wn = wid & 1;
    const int lq = lane >> 4, lr = lane & 15;
    // bijective XCD slab swizzle (dispatch order is x-fastest: f = x + y*256)
    const int f  = blockIdx.y * gridDim.x + blockIdx.x;
    const int xc = f & 7, sl = f >> 3;       // sl in [0,384)
    const int ml = sl / 12, nn = sl % 12;    // 32 m-panels per XCD, n fastest
    const int m0 = (xc * 32 + ml) * 128;
    const int n0 = nn * 128;
    const int lrow = lane >> 3;              // staging: row within 8-row group
    const int lsw  = ((lane & 7) ^ lrow) * 8; // swizzled source chunk (elems)

    f32x4 acc[4][4] = {};

    for (int kb = 0; kb < DIM; kb += 64) {
#pragma unroll
        for (int t = 0; t < 4; ++t) {
            int qi = wid * 4 + t;            // instruction index 0..15
            int row = qi * 8 + lrow;
            gl_lds16(&xb[(size_t)(m0 + row) * DIM + kb + lsw], &As[qi * 512]);
            gl_lds16(&wqkv_t[(size_t)(n0 + row) * DIM + kb + lsw], &Bs[qi * 512]);
        }
        __syncthreads();
#pragma unroll
        for (int ks = 0; ks < 2; ++ks) {
            const int csw = ((ks * 4 + lq) ^ (lr & 7)) * 8;  // swizzled read slot
            bf16x8 af[4], bfv[4];
#pragma unroll
            for (int i = 0; i < 4; ++i)
                af[i] = *reinterpret_cast<const bf16x8*>(
                    &As[(wm * 64 + i * 16 + lr) * 64 + csw]);
#pragma unroll
            for (int j = 0; j < 4; ++j)
                bfv[j] = *reinterpret_cast<const bf16x8*>(
                    &Bs[(wn * 64 + j * 16 + lr) * 64 + csw]);
#pragma unroll
            for (int i = 0; i < 4; ++i)
#pragma unroll
                for (int j = 0; j < 4; ++j)
                    acc[i][j] = MFMA16(af[i], bfv[j], acc[i][j]);
        }
        __syncthreads();
    }

    const int which = n0 / INNER;            // 0=q 1=k 2=v (block-uniform)
    const int n0w = n0 % INNER;
    const int b = m0 / SEQ;
    const int nbase = m0 % SEQ;

    if (which == 0) {
        // T[row][col]: scalar writes with elu, then coalesced [n][dh] stores
#pragma unroll
        for (int i = 0; i < 4; ++i)
#pragma unroll
            for (int j = 0; j < 4; ++j) {
                int col = wn * 64 + j * 16 + lr;
#pragma unroll
                for (int r = 0; r < 4; ++r)
                    T[(wm * 64 + i * 16 + lq * 4 + r) * TSTR + col] =
                        (__bf16)elu1(acc[i][j][r]);
            }
        __syncthreads();
#pragma unroll
        for (int it = 0; it < 8; ++it) {
            int c = tid + it * 256;          // 2048 chunks of 8
            int row = c >> 4, dc = (c & 15) * 8;
            bf16x8 v = *reinterpret_cast<const bf16x8*>(&T[row * TSTR + dc]);
            int col = n0w + dc;
            int h = col >> 6, d = col & 63;
            *reinterpret_cast<bf16x8*>(
                &q_ws[(((size_t)(b * HEADS + h)) * SEQ + nbase + row) * DH + d]) = v;
        }
    } else {
        __bf16* dst = (which == 1) ? kT_ws : vT_ws;
        // T[col][row]: vector 8B writes, then coalesced [dh][n] stores
#pragma unroll
        for (int i = 0; i < 4; ++i)
#pragma unroll
            for (int j = 0; j < 4; ++j) {
                int col = wn * 64 + j * 16 + lr;
                int rowb = wm * 64 + i * 16 + lq * 4;
                bf16x4 h4;
#pragma unroll
                for (int r = 0; r < 4; ++r) {
                    float v = acc[i][j][r];
                    h4[r] = (__bf16)((which == 1) ? elu1(v) : v);
                }
                *reinterpret_cast<bf16x4*>(&T[col * TSTR + rowb]) = h4;
            }
        __syncthreads();
#pragma unroll
        for (int it = 0; it < 8; ++it) {
            int c = tid + it * 256;
            int colIdx = c >> 4, rc = (c & 15) * 8;
            bf16x8 v = *reinterpret_cast<const bf16x8*>(&T[colIdx * TSTR + rc]);
            int gcol = n0w + colIdx;
            int h = gcol >> 6, d = gcol & 63;
            *reinterpret_cast<bf16x8*>(
                &dst[(((size_t)(b * HEADS + h)) * DH + d) * SEQ + nbase + rc]) = v;
        }
    }
}

// ---------------- shared 256x256 GEMM core (K=512), counted-vmcnt schedule ----
__device__ __forceinline__ void gemm256_core(
    const __bf16* __restrict__ Am, const __bf16* __restrict__ Bm,
    int m0, int n0, char* smem, f32x4 acc[8][4])
{
    const int tid = threadIdx.x;
    const int wid = tid >> 6;
    const int lane = tid & 63;
    const int wm = wid >> 2, wn = wid & 3;
    const int lq = lane >> 4, lr = lane & 15;
    const int lrow = lane >> 3;
    const int lsw  = ((lane & 7) ^ lrow) * 8;     // pre-swizzled source chunk

    __bf16* const As0 = (__bf16*)smem;            // [256][64]
    __bf16* const Bs0 = (__bf16*)(smem + 32768);  // [256][64]
    __bf16* const As1 = (__bf16*)(smem + 65536);
    __bf16* const Bs1 = (__bf16*)(smem + 98304);

    const int csw0 = ((0 + lq) ^ (lr & 7)) * 8;   // ks=0 read slot
    const int csw1 = ((4 + lq) ^ (lr & 7)) * 8;   // ks=1 read slot

    auto stageB = [&](__bf16* Bs, int kt, int u) {
        gl_lds16(&Bm[(size_t)(n0 + u * 64 + wid * 8 + lrow) * 512 + kt * 64 + lsw],
                 Bs + (u * 64 + wid * 8) * 64);
    };
    auto stageA = [&](__bf16* As, int kt, int s2) {
        int gr = (wid < 4) ? (s2 * 32 + wid * 8) : (128 + s2 * 32 + (wid - 4) * 8);
        gl_lds16(&Am[(size_t)(m0 + gr + lrow) * 512 + kt * 64 + lsw],
                 As + gr * 64);
    };
    auto ldA = [&](const __bf16* As, int m, int csw) -> bf16x8 {
        return *reinterpret_cast<const bf16x8*>(As + (wm * 128 + m * 16 + lr) * 64 + csw);
    };
    auto ldB = [&](const __bf16* Bs, int n, int csw) -> bf16x8 {
        return *reinterpret_cast<const bf16x8*>(Bs + (wn * 64 + n * 16 + lr) * 64 + csw);
    };

    // prologue: tile 0 in consumption order
    stageB(Bs0, 0, 0); stageB(Bs0, 0, 1); stageB(Bs0, 0, 2); stageB(Bs0, 0, 3);
    stageA(As0, 0, 0); stageA(As0, 0, 1); stageA(As0, 0, 2); stageA(As0, 0, 3);
    asm volatile("s_waitcnt vmcnt(3)" ::: "memory");
    BARRIER();

#pragma unroll 2
    for (int t = 0; t < 8; ++t) {
        __bf16* const As  = (t & 1) ? As1 : As0;
        __bf16* const Bs  = (t & 1) ? Bs1 : Bs0;
        __bf16* const Asn = (t & 1) ? As0 : As1;
        __bf16* const Bsn = (t & 1) ? Bs0 : Bs1;
        const bool pf = (t < 7);
        bf16x8 bfr[4][2];

        // ---- phase 0: m=0,1 (A stripe 0) + all B frags ----
        {
            bf16x8 a00 = ldA(As, 0, csw0), a01 = ldA(As, 0, csw1);
            bf16x8 a10 = ldA(As, 1, csw0), a11 = ldA(As, 1, csw1);
#pragma unroll
            for (int n = 0; n < 4; ++n) { bfr[n][0] = ldB(Bs, n, csw0); bfr[n][1] = ldB(Bs, n, csw1); }
            if (pf) { stageB(Bsn, t + 1, 0); stageB(Bsn, t + 1, 1); }
            __builtin_amdgcn_s_setprio(1);
#pragma unroll
            for (int n = 0; n < 4; ++n) {
                acc[0][n] = MFMA16(a00, bfr[n][0], acc[0][n]);
                acc[0][n] = MFMA16(a01, bfr[n][1], acc[0][n]);
                acc[1][n] = MFMA16(a10, bfr[n][0], acc[1][n]);
                acc[1][n] = MFMA16(a11, bfr[n][1], acc[1][n]);
            }
            __builtin_amdgcn_s_setprio(0);
            if (pf) asm volatile("s_waitcnt vmcnt(4)" ::: "memory");
            else    asm volatile("s_waitcnt vmcnt(2)" ::: "memory");
            BARRIER();
        }
        // ---- phase 1: m=2,3 (A stripe 1) ----
        {
            bf16x8 a00 = ldA(As, 2, csw0), a01 = ldA(As, 2, csw1);
            bf16x8 a10 = ldA(As, 3, csw0), a11 = ldA(As, 3, csw1);
            if (pf) { stageB(Bsn, t + 1, 2); stageB(Bsn, t + 1, 3); }
            __builtin_amdgcn_s_setprio(1);
#pragma unroll
            for (int n = 0; n < 4; ++n) {
                acc[2][n] = MFMA16(a00, bfr[n][0], acc[2][n]);
                acc[2][n] = MFMA16(a01, bfr[n][1], acc[2][n]);
                acc[3][n] = MFMA16(a10, bfr[n][0], acc[3][n]);
                acc[3][n] = MFMA16(a11, bfr[n][1], acc[3][n]);
            }
            __builtin_amdgcn_s_setprio(0);
            if (pf) asm volatile("s_waitcnt vmcnt(5)" ::: "memory");
            else    asm volatile("s_waitcnt vmcnt(1)" ::: "memory");
            BARRIER();
        }
        // ---- phase 2: m=4,5 (A stripe 2) ----
        {
            bf16x8 a00 = ldA(As, 4, csw0), a01 = ldA(As, 4, csw1);
            bf16x8 a10 = ldA(As, 5, csw0), a11 = ldA(As, 5, csw1);
            if (pf) { stageA(Asn, t + 1, 0); stageA(Asn, t + 1, 1); }
            __builtin_amdgcn_s_setprio(1);
#pragma unroll
            for (int n = 0; n < 4; ++n) {
                acc[4][n] = MFMA16(a00, bfr[n][0], acc[4][n]);
                acc[4][n] = MFMA16(a01, bfr[n][1], acc[4][n]);
                acc[5][n] = MFMA16(a10, bfr[n][0], acc[5][n]);
                acc[5][n] = MFMA16(a11, bfr[n][1], acc[5][n]);
            }
            __builtin_amdgcn_s_setprio(0);
            if (pf) asm volatile("s_waitcnt vmcnt(6)" ::: "memory");
            else    asm volatile("s_waitcnt vmcnt(0)" ::: "memory");
            BARRIER();
        }
        // ---- phase 3: m=6,7 (A stripe 3) ----
        {
            bf16x8 a00 = ldA(As, 6, csw0), a01 = ldA(As, 6, csw1);
            bf16x8 a10 = ldA(As, 7, csw0), a11 = ldA(As, 7, csw1);
            if (pf) { stageA(Asn, t + 1, 2); stageA(Asn, t + 1, 3); }
            __builtin_amdgcn_s_setprio(1);
#pragma unroll
            for (int n = 0; n < 4; ++n) {
                acc[6][n] = MFMA16(a00, bfr[n][0], acc[6][n]);
                acc[6][n] = MFMA16(a01, bfr[n][1], acc[6][n]);
                acc[7][n] = MFMA16(a10, bfr[n][0], acc[7][n]);
                acc[7][n] = MFMA16(a11, bfr[n][1], acc[7][n]);
            }
            __builtin_amdgcn_s_setprio(0);
            if (pf) asm volatile("s_waitcnt vmcnt(3)" ::: "memory");
            BARRIER();
        }
    }
}

// ---------------- K2: kv_reduce, double-buffered (T14 issue-early/write-late) -
__launch_bounds__(256, 2)
__global__ void kv_reduce(const __bf16* __restrict__ kT,
                          const __bf16* __restrict__ vT,
                          float* __restrict__ kv_t,     // [bh][m][d] fp32
                          float* __restrict__ ksum) {   // [bh][d]
    __shared__ __attribute__((aligned(16))) __bf16 Ks[2][64][136];
    __shared__ __attribute__((aligned(16))) __bf16 Vs[2][64][136];
    const int tid = threadIdx.x;
    const int wid = tid >> 6;
    const int lane = tid & 63;
    const int lq = lane >> 4, lr = lane & 15;
    const int bh = blockIdx.y;
    const int n0 = blockIdx.x * 512;
    const size_t base = (size_t)bh * DH * SEQ;
    f32x4 acc[4] = {};
    f32x4 acc1 = {};
    bf16x8 ones8;
#pragma unroll
    for (int e = 0; e < 8; ++e) ones8[e] = (__bf16)1.f;

    const int srow = tid >> 4, skc = (tid & 15) * 8;   // this thread's 4 rows
    bf16x8 kr[4], vr[4];
    auto load_regs = [&](int ch) {
        int nc = n0 + ch * 128;
#pragma unroll
        for (int t = 0; t < 4; ++t) {
            int row = srow + t * 16;
            kr[t] = *reinterpret_cast<const bf16x8*>(&kT[base + (size_t)row * SEQ + nc + skc]);
            vr[t] = *reinterpret_cast<const bf16x8*>(&vT[base + (size_t)row * SEQ + nc + skc]);
        }
    };
    auto st_lds = [&](int buf) {
#pragma unroll
        for (int t = 0; t < 4; ++t) {
            int row = srow + t * 16;
            *reinterpret_cast<bf16x8*>(&Ks[buf][row][skc]) = kr[t];
            *reinterpret_cast<bf16x8*>(&Vs[buf][row][skc]) = vr[t];
        }
    };

    load_regs(0); st_lds(0);
    __syncthreads();
    for (int ch = 0; ch < 4; ++ch) {
        const int buf = ch & 1;
        if (ch < 3) load_regs(ch + 1);          // loads in flight under MFMAs
#pragma unroll
        for (int ks = 0; ks < 4; ++ks) {
            bf16x8 a = *reinterpret_cast<const bf16x8*>(&Ks[buf][wid * 16 + lr][ks * 32 + lq * 8]);
            acc1 = MFMA16(a, ones8, acc1);
#pragma unroll
            for (int j = 0; j < 4; ++j) {
                bf16x8 b = *reinterpret_cast<const bf16x8*>(&Vs[buf][j * 16 + lr][ks * 32 + lq * 8]);
                acc[j] = MFMA16(a, b, acc[j]);
            }
        }
        if (ch < 3) st_lds(buf ^ 1);            // write-late into other buffer
        __syncthreads();
    }
    float* dst = kv_t + (size_t)bh * DH * DH;
#pragma unroll
    for (int j = 0; j < 4; ++j) {
        int m = j * 16 + lr;
#pragma unroll
        for (int r = 0; r < 4; ++r) {
            int d = wid * 16 + lq * 4 + r;
            atomicAdd(&dst[m * DH + d], acc[j][r]);
        }
    }
    if (lr == 0) {
#pragma unroll
        for (int r = 0; r < 4; ++r)
            atomicAdd(&ksum[bh * DH + wid * 16 + lq * 4 + r], acc1[r]);
    }
}

// ---------------- K3: attn[b][n][h*64+m] = z * (q @ kv) -----------------------
// z-phase vectorized: 4x ds_read_b128 per thread (was 32x ds_read_u16).
__launch_bounds__(256, 2)
__global__ void attn_kernel(const __bf16* __restrict__ q_ws,
                            const float* __restrict__ kv_t,
                            const float* __restrict__ ksum,
                            __bf16* __restrict__ attn) {
    __shared__ __attribute__((aligned(16))) __bf16 Qs[128][72];
    __shared__ __attribute__((aligned(16))) __bf16 KVs[64][72];
    __shared__ float zs[128];
    __shared__ float ks_s[64];
    const int tid = threadIdx.x;
    const int wid = tid >> 6, lane = tid & 63;
    const int lq = lane >> 4, lr = lane & 15;
    const int bh = blockIdx.y;
    const int b = bh >> 3, h = bh & 7;
    const int n0 = blockIdx.x * 128;
    const size_t qbase = ((size_t)bh * SEQ + n0) * DH;

#pragma unroll
    for (int t = 0; t < 4; ++t) {
        int c = tid + t * 256;                    // 128 rows x 8 chunks
        int row = c >> 3, kc = (c & 7) * 8;
        *reinterpret_cast<bf16x8*>(&Qs[row][kc]) =
            *reinterpret_cast<const bf16x8*>(&q_ws[qbase + (size_t)row * DH + kc]);
    }
    const float* kvsrc = kv_t + (size_t)bh * DH * DH;
#pragma unroll
    for (int t = 0; t < 4; ++t) {
        int c = tid + t * 256;                    // 64 rows x 16 float4
        int m = c >> 4, dc = (c & 15) * 4;
        float4 f = *reinterpret_cast<const float4*>(&kvsrc[m * DH + dc]);
        bf16x4 h4 = {(__bf16)f.x, (__bf16)f.y, (__bf16)f.z, (__bf16)f.w};
        *reinterpret_cast<bf16x4*>(&KVs[m][dc]) = h4;
    }
    if (tid < 64) ks_s[tid] = ksum[bh * DH + tid];
    __syncthreads();
    {
        int row = tid >> 1, part = tid & 1;
        float s = 0.f;
#pragma unroll
        for (int c = 0; c < 4; ++c) {
            bf16x8 v = *reinterpret_cast<const bf16x8*>(&Qs[row][part * 32 + c * 8]);
            const float* kp = &ks_s[part * 32 + c * 8];
#pragma unroll
            for (int j = 0; j < 8; ++j) s += (float)v[j] * kp[j];
        }
        s += __shfl_xor(s, 1, 64);
        if (part == 0) zs[row] = 1.f / (s + 1e-6f);
    }
    __syncthreads();

    f32x4 acc[2][4] = {};
#pragma unroll
    for (int ks = 0; ks < 2; ++ks) {
        bf16x8 a0 = *reinterpret_cast<const bf16x8*>(&Qs[wid * 32 + lr][ks * 32 + lq * 8]);
        bf16x8 a1 = *reinterpret_cast<const bf16x8*>(&Qs[wid * 32 + 16 + lr][ks * 32 + lq * 8]);
#pragma unroll
        for (int j = 0; j < 4; ++j) {
            bf16x8 bfr = *reinterpret_cast<const bf16x8*>(&KVs[j * 16 + lr][ks * 32 + lq * 8]);
            acc[0][j] = MFMA16(a0, bfr, acc[0][j]);
            acc[1][j] = MFMA16(a1, bfr, acc[1][j]);
        }
    }
    // transpose through LDS (reuse Qs) for coalesced bf16x8 stores
    __syncthreads();
#pragma unroll
    for (int mt = 0; mt < 2; ++mt)
#pragma unroll
        for (int j = 0; j < 4; ++j) {
            int m = j * 16 + lr;
#pragma unroll
            for (int r = 0; r < 4; ++r) {
                int row = wid * 32 + mt * 16 + lq * 4 + r;
                Qs[row][m] = (__bf16)(acc[mt][j][r] * zs[row]);
            }
        }
    __syncthreads();
#pragma unroll
    for (int it = 0; it < 4; ++it) {
        int c = tid + it * 256;                   // 1024 chunks: 128 rows x 8
        int row = c >> 3, mc = (c & 7) * 8;
        bf16x8 v = *reinterpret_cast<const bf16x8*>(&Qs[row][mc]);
        *reinterpret_cast<bf16x8*>(
            &attn[((size_t)(b * SEQ + n0 + row)) * INNER + h * DH + mc]) = v;
    }
}

// ---------------- K4: out = attn @ w_out + b_out (fp32 out), 256^2 core ------
__launch_bounds__(512, 2)
__global__ void gemm_out(const __bf16* __restrict__ attn,
                         const __bf16* __restrict__ wout_t,
                         const float* __restrict__ b_out,
                         float* __restrict__ out) {
    __shared__ __attribute__((aligned(16))) char smem[131072];
    // bijective XCD swizzle: 256 blocks = 8 x 32
    const int f  = blockIdx.y * gridDim.x + blockIdx.x;
    const int xc = f & 7, sl = f >> 3;            // sl in [0,32)
    const int m0 = (xc * 16 + (sl >> 1)) * 256;
    const int n0 = (sl & 1) * 256;

    f32x4 acc[8][4] = {};
    gemm256_core(attn, wout_t, m0, n0, smem, acc);

    const int tid = threadIdx.x;
    const int wid = tid >> 6;
    const int lane = tid & 63;
    const int wm = wid >> 2, wn = wid & 3;
    const int lq = lane >> 4, lr = lane & 15;

#pragma unroll
    for (int n = 0; n < 4; ++n) {
        int col = n0 + wn * 64 + n * 16 + lr;
        float bias = b_out[col];
#pragma unroll
        for (int m = 0; m < 8; ++m) {
            int row = m0 + wm * 128 + m * 16 + lq * 4;
#pragma unroll
            for (int r = 0; r < 4; ++r)
                out[(size_t)(row + r) * DIM + col] = acc[m][n][r] + bias;
        }
    }
}

// ------------------------------------------------------------------------------
extern "C" void kernel_launch(void* const* d_in, const int* in_sizes, int n_in,
                              void* d_out, int out_size, void* d_ws, size_t ws_size,
                              hipStream_t stream) {
    (void)in_sizes; (void)n_in; (void)out_size; (void)ws_size;
    const float* x     = (const float*)d_in[0];
    const float* w_qkv = (const float*)d_in[1];
    const float* w_out = (const float*)d_in[2];
    const float* b_out = (const float*)d_in[3];
    float* out = (float*)d_out;

    char* ws = (char*)d_ws;
    size_t off = 0;
    auto alloc = [&](size_t bytes) {
        char* p = ws + off;
        off += (bytes + 255) & ~(size_t)255;
        return p;
    };
    // xb (bf16 x) aliases attn: xb dead after gemm_qkv, attn born at attn_kernel
    __bf16* xb     = (__bf16*)alloc((size_t)M_TOT * DIM * 2);    // 33.5 MB
    __bf16* attn   = xb;                                         // alias (same size)
    __bf16* q_ws   = (__bf16*)alloc((size_t)BHN * SEQ * DH * 2);
    __bf16* kT_ws  = (__bf16*)alloc((size_t)BHN * SEQ * DH * 2);
    __bf16* vT_ws  = (__bf16*)alloc((size_t)BHN * SEQ * DH * 2);
    float*  kv_t   = (float*)alloc((size_t)BHN * DH * DH * 4 + (size_t)BHN * DH * 4);
    float*  ksum   = kv_t + (size_t)BHN * DH * DH;
    __bf16* wqkv_t = (__bf16*)alloc((size_t)QKV_COLS * DIM * 2);
    __bf16* wout_t = (__bf16*)alloc((size_t)INNER * DIM * 2);

    hipMemsetAsync(kv_t, 0, (size_t)BHN * DH * DH * 4 + (size_t)BHN * DH * 4, stream);
    convert_all<<<dim3(XBLKS + 768 + 256), 256, 0, stream>>>(
        x, w_qkv, w_out, xb, wqkv_t, wout_t);
    gemm_qkv<<<dim3(M_TOT / 128, QKV_COLS / 128), 256, 0, stream>>>(
        xb, wqkv_t, q_ws, kT_ws, vT_ws);
    kv_reduce<<<dim3(16, BHN), 256, 0, stream>>>(kT_ws, vT_ws, kv_t, ksum);
    attn_kernel<<<dim3(SEQ / 128, BHN), 256, 0, stream>>>(q_ws, kv_t, ksum, attn);
    gemm_out<<<dim3(M_TOT / 256, DIM / 256), 512, 0, stream>>>(attn, wout_t, b_out, out);
}